// Round 19
// baseline (159.407 us; speedup 1.0000x reference)
//
#include <hip/hip_runtime.h>
#include <hip/hip_bf16.h>
#include <math.h>

#define S 4096
#define D 512
#define H 8
#define DK 64
#define WIN 128

typedef __attribute__((ext_vector_type(8))) short bf16x8;
typedef __attribute__((ext_vector_type(4))) float f32x4;

__device__ __forceinline__ unsigned short f2bf(float f) {
    __hip_bfloat16 h = __float2bfloat16(f);
    return *(unsigned short*)&h;
}
__device__ __forceinline__ float bf2f(unsigned short u) {
    unsigned int x = ((unsigned int)u) << 16;
    return __uint_as_float(x);
}
__device__ __forceinline__ bf16x8 cvt8(const float* p) {
    float4 a = *(const float4*)&p[0];
    float4 b = *(const float4*)&p[4];
    unsigned short o[8] = {f2bf(a.x), f2bf(a.y), f2bf(a.z), f2bf(a.w),
                           f2bf(b.x), f2bf(b.y), f2bf(b.z), f2bf(b.w)};
    return *(const bf16x8*)o;
}

// ---------------------------------------------------------------------------
// proj3: C = x @ W^T + b for q,k (bf16 row-major out) and v (bf16 transposed
// out -> vT[col*4096+row]). A = fp32 x with inline cvt; W fp32 staged w/ cvt.
// BM=128, BN=64, BK-split 2x256. Grid (32, 8, 3).
// ---------------------------------------------------------------------------
__global__ __launch_bounds__(256) void proj3_kernel(
    const float* __restrict__ x,
    const float* __restrict__ wq, const float* __restrict__ bq,
    const float* __restrict__ wk, const float* __restrict__ bk,
    const float* __restrict__ wv, const float* __restrict__ bv,
    unsigned short* __restrict__ qb, unsigned short* __restrict__ kb,
    unsigned short* __restrict__ vT)
{
    __shared__ unsigned short Bs[64][264];   // 33.8 KB

    const float* W; const float* bias;
    unsigned short* CB; unsigned short* CBT;
    if (blockIdx.z == 0)      { W = wq; bias = bq; CB = qb;      CBT = nullptr; }
    else if (blockIdx.z == 1) { W = wk; bias = bk; CB = kb;      CBT = nullptr; }
    else                      { W = wv; bias = bv; CB = nullptr; CBT = vT; }

    const int tid  = threadIdx.x;
    const int m0   = blockIdx.x * 128;
    const int n0   = blockIdx.y * 64;
    const int wv_  = tid >> 6;
    const int lane = tid & 63;
    const int l16  = lane & 15;
    const int klo  = (lane >> 4) * 8;

    const float* arow0 = &x[(size_t)(m0 + wv_ * 32 + l16) * 512 + klo];
    const float* arow1 = arow0 + 16 * 512;

    f32x4 acc[2][4];
    #pragma unroll
    for (int r = 0; r < 2; ++r)
        #pragma unroll
        for (int nf = 0; nf < 4; ++nf)
            acc[r][nf] = (f32x4){0.f, 0.f, 0.f, 0.f};

    #pragma unroll
    for (int half = 0; half < 2; ++half) {
        const int kbase = half * 256;
        #pragma unroll
        for (int it = 0; it < 8; ++it) {
            const int c   = tid + it * 256;
            const int row = c >> 5;
            const int kc  = (c & 31) * 8;
            bf16x8 w8 = cvt8(&W[(size_t)(n0 + row) * 512 + kbase + kc]);
            *(bf16x8*)&Bs[row][kc] = w8;
        }
        __syncthreads();

        #pragma unroll 4
        for (int kb = 0; kb < 256; kb += 32) {
            bf16x8 a0 = cvt8(&arow0[kbase + kb]);
            bf16x8 a1 = cvt8(&arow1[kbase + kb]);
            #pragma unroll
            for (int nf = 0; nf < 4; ++nf) {
                bf16x8 b = *(const bf16x8*)&Bs[nf * 16 + l16][kb + klo];
                acc[0][nf] = __builtin_amdgcn_mfma_f32_16x16x32_bf16(a0, b, acc[0][nf], 0, 0, 0);
                acc[1][nf] = __builtin_amdgcn_mfma_f32_16x16x32_bf16(a1, b, acc[1][nf], 0, 0, 0);
            }
        }
        __syncthreads();
    }

    const int r0 = (lane >> 4) * 4;
    #pragma unroll
    for (int r = 0; r < 2; ++r) {
        #pragma unroll
        for (int nf = 0; nf < 4; ++nf) {
            const int col = n0 + nf * 16 + l16;
            const float bb = bias[col];
            if (CBT) {
                ushort4 o;
                o.x = f2bf(acc[r][nf][0] + bb);
                o.y = f2bf(acc[r][nf][1] + bb);
                o.z = f2bf(acc[r][nf][2] + bb);
                o.w = f2bf(acc[r][nf][3] + bb);
                const int row0 = m0 + wv_ * 32 + r * 16 + r0;
                *(ushort4*)&CBT[(size_t)col * 4096 + row0] = o;
            } else {
                #pragma unroll
                for (int vv = 0; vv < 4; ++vv) {
                    const int row = m0 + wv_ * 32 + r * 16 + r0 + vv;
                    CB[(size_t)row * 512 + col] = f2bf(acc[r][nf][vv] + bb);
                }
            }
        }
    }
}

// ---------------------------------------------------------------------------
// outproj: out = ctxb @ wo^T + bo (fp32 out). A = bf16 ctxb; wo fp32 staged.
// ---------------------------------------------------------------------------
__global__ __launch_bounds__(256) void outproj_kernel(
    const unsigned short* __restrict__ ctxb,
    const float* __restrict__ wo, const float* __restrict__ bo,
    float* __restrict__ out)
{
    __shared__ unsigned short Bs[64][264];

    const int tid  = threadIdx.x;
    const int m0   = blockIdx.x * 128;
    const int n0   = blockIdx.y * 64;
    const int wv_  = tid >> 6;
    const int lane = tid & 63;
    const int l16  = lane & 15;
    const int klo  = (lane >> 4) * 8;

    const unsigned short* arow0 = &ctxb[(size_t)(m0 + wv_ * 32 + l16) * 512 + klo];
    const unsigned short* arow1 = arow0 + 16 * 512;

    f32x4 acc[2][4];
    #pragma unroll
    for (int r = 0; r < 2; ++r)
        #pragma unroll
        for (int nf = 0; nf < 4; ++nf)
            acc[r][nf] = (f32x4){0.f, 0.f, 0.f, 0.f};

    #pragma unroll
    for (int half = 0; half < 2; ++half) {
        const int kbase = half * 256;
        #pragma unroll
        for (int it = 0; it < 8; ++it) {
            const int c   = tid + it * 256;
            const int row = c >> 5;
            const int kc  = (c & 31) * 8;
            bf16x8 w8 = cvt8(&wo[(size_t)(n0 + row) * 512 + kbase + kc]);
            *(bf16x8*)&Bs[row][kc] = w8;
        }
        __syncthreads();

        #pragma unroll 4
        for (int kb = 0; kb < 256; kb += 32) {
            bf16x8 a0 = *(const bf16x8*)&arow0[kbase + kb];
            bf16x8 a1 = *(const bf16x8*)&arow1[kbase + kb];
            #pragma unroll
            for (int nf = 0; nf < 4; ++nf) {
                bf16x8 b = *(const bf16x8*)&Bs[nf * 16 + l16][kb + klo];
                acc[0][nf] = __builtin_amdgcn_mfma_f32_16x16x32_bf16(a0, b, acc[0][nf], 0, 0, 0);
                acc[1][nf] = __builtin_amdgcn_mfma_f32_16x16x32_bf16(a1, b, acc[1][nf], 0, 0, 0);
            }
        }
        __syncthreads();
    }

    const int r0 = (lane >> 4) * 4;
    #pragma unroll
    for (int r = 0; r < 2; ++r) {
        #pragma unroll
        for (int nf = 0; nf < 4; ++nf) {
            const int col = n0 + nf * 16 + l16;
            const float bb = bo[col];
            #pragma unroll
            for (int vv = 0; vv < 4; ++vv) {
                const int row = m0 + wv_ * 32 + r * 16 + r0 + vv;
                out[(size_t)row * 512 + col] = acc[r][nf][vv] + bb;
            }
        }
    }
}

// ---------------------------------------------------------------------------
// Fused band attention (round-18, verified): wave-local K/V staging (no
// chunk-loop barriers), bf16 P, store/PV interleave. QB=16, grid (256, 8).
// ---------------------------------------------------------------------------
__global__ __launch_bounds__(256) void band_attn_kernel(
    const unsigned short* __restrict__ qb, const unsigned short* __restrict__ kb,
    const unsigned short* __restrict__ vT,
    float* __restrict__ attn, unsigned short* __restrict__ ctxb)
{
    __shared__ __align__(16) unsigned short KV[64][72];   // K:[key][d] / V:[d][s]
    __shared__ __align__(16) unsigned short Pb[16][344];  // exp-scores, bf16
    __shared__ float rinvs[16];

    const int tid = threadIdx.x;
    const int h  = blockIdx.y;
    const int q0 = blockIdx.x * 16;
    const int w0 = q0 - 128;

    const int wv   = tid >> 6;
    const int lane = tid & 63;
    const int l16  = lane & 15;
    const int klo  = (lane >> 4) * 8;
    const int r0   = (lane >> 4) * 4;

    const int l16s = lane & 15;
    const int ds0  = (lane >> 4) * 16;

    const unsigned short* qrow = &qb[(size_t)(q0 + l16) * 512 + h * 64 + klo];
    const bf16x8 aq0 = *(const bf16x8*)&qrow[0];
    const bf16x8 aq1 = *(const bf16x8*)&qrow[32];

    // ================= QK^T phase (wave-local K staging, no barriers) ======
    for (int ch = 0; ch < 5; ++ch) {
        const int c0 = w0 + ch * 64;
        if (c0 + 64 <= 0 || c0 >= S) continue;
        {
            const int krow = min(max(c0 + wv * 16 + l16s, 0), S - 1);
            const unsigned short* src = &kb[(size_t)krow * 512 + h * 64 + ds0];
            *(bf16x8*)&KV[wv * 16 + l16s][ds0]     = *(const bf16x8*)&src[0];
            *(bf16x8*)&KV[wv * 16 + l16s][ds0 + 8] = *(const bf16x8*)&src[8];
        }
        f32x4 acc = (f32x4){0.f, 0.f, 0.f, 0.f};
        bf16x8 b0 = *(const bf16x8*)&KV[wv * 16 + l16][klo];
        bf16x8 b1 = *(const bf16x8*)&KV[wv * 16 + l16][32 + klo];
        acc = __builtin_amdgcn_mfma_f32_16x16x32_bf16(aq0, b0, acc, 0, 0, 0);
        acc = __builtin_amdgcn_mfma_f32_16x16x32_bf16(aq1, b1, acc, 0, 0, 0);
        #pragma unroll
        for (int vv = 0; vv < 4; ++vv)
            Pb[r0 + vv][ch * 64 + wv * 16 + l16] = f2bf(acc[vv] * 0.125f);
    }
    __syncthreads();                               // barrier 1

    // ---- softmax: exp in band, ZERO outside band (cols [0,320)) ----
    {
        const int r   = tid >> 4;
        const int lx  = tid & 15;
        const int i   = q0 + r;
        const int lo = max(i - WIN, 0) - w0;
        const int hi = min(i + WIN, S - 1) - w0;

        float m = -1e30f;
        for (int c = lo + lx; c <= hi; c += 16) m = fmaxf(m, bf2f(Pb[r][c]));
        m = fmaxf(m, __shfl_xor(m, 1));
        m = fmaxf(m, __shfl_xor(m, 2));
        m = fmaxf(m, __shfl_xor(m, 4));
        m = fmaxf(m, __shfl_xor(m, 8));

        float sum = 0.f;
        for (int c = lx; c < 320; c += 16) {
            unsigned short pe = 0;
            if (c >= lo && c <= hi) {
                float e = __expf(bf2f(Pb[r][c]) - m);
                sum += e;
                pe = f2bf(e);
            }
            Pb[r][c] = pe;
        }
        sum += __shfl_xor(sum, 1);
        sum += __shfl_xor(sum, 2);
        sum += __shfl_xor(sum, 4);
        sum += __shfl_xor(sum, 8);
        if (lx == 0) rinvs[r] = 1.0f / sum;
    }
    __syncthreads();                               // barrier 2 (last)

    float* rowbase = attn + (size_t)h * S * S;
    auto write_row = [&](int r) {
        const int i = q0 + r;
        float* rowp = rowbase + (size_t)i * S;
        const int lo = max(i - WIN, 0) - w0;
        const int hi = min(i + WIN, S - 1) - w0;
        const float rv = rinvs[r];
        #pragma unroll
        for (int t = 0; t < 4; ++t) {
            const int c4 = (tid + t * 256) << 2;
            const int lc = c4 - w0;
            float4 o;
            if (lc >= lo && lc + 3 <= hi) {
                ushort4 p = *(const ushort4*)&Pb[r][lc];
                o.x = bf2f(p.x) * rv; o.y = bf2f(p.y) * rv;
                o.z = bf2f(p.z) * rv; o.w = bf2f(p.w) * rv;
            } else if (lc + 3 < lo || lc > hi) {
                o = make_float4(0.f, 0.f, 0.f, 0.f);
            } else {
                o.x = (lc + 0 >= lo && lc + 0 <= hi) ? bf2f(Pb[r][lc + 0]) * rv : 0.f;
                o.y = (lc + 1 >= lo && lc + 1 <= hi) ? bf2f(Pb[r][lc + 1]) * rv : 0.f;
                o.z = (lc + 2 >= lo && lc + 2 <= hi) ? bf2f(Pb[r][lc + 2]) * rv : 0.f;
                o.w = (lc + 3 >= lo && lc + 3 <= hi) ? bf2f(Pb[r][lc + 3]) * rv : 0.f;
            }
            *(float4*)&rowp[c4] = o;
        }
    };

    // ====== PV phase (wave-local V staging) interleaved with attn stores ===
    f32x4 pacc = (f32x4){0.f, 0.f, 0.f, 0.f};
    const unsigned short* vtd = &vT[((size_t)h * 64 + wv * 16 + l16s) * 4096];
    int wrow = 0;
    for (int ch = 0; ch < 5; ++ch) {
        const int c0 = w0 + ch * 64;
        const bool live = (c0 + 64 > 0) && (c0 < S);
        bf16x8 v0, v1;
        if (live) {
            const int offs = min(max(c0 + ds0, 0), S - 16);
            v0 = *(const bf16x8*)&vtd[offs];
            v1 = *(const bf16x8*)&vtd[offs + 8];
        }
        #pragma unroll 1
        for (int k2 = 0; k2 < 3 && wrow < 16; ++k2, ++wrow) write_row(wrow);
        if (live) {
            *(bf16x8*)&KV[wv * 16 + l16s][ds0]     = v0;
            *(bf16x8*)&KV[wv * 16 + l16s][ds0 + 8] = v1;
            #pragma unroll
            for (int kk = 0; kk < 64; kk += 32) {
                bf16x8 a = *(const bf16x8*)&Pb[l16][ch * 64 + kk + klo];
                bf16x8 b = *(const bf16x8*)&KV[wv * 16 + l16][kk + klo];
                pacc = __builtin_amdgcn_mfma_f32_16x16x32_bf16(a, b, pacc, 0, 0, 0);
            }
        }
    }
    #pragma unroll 1
    while (wrow < 16) write_row(wrow++);

    // ---- ctx write ----
    #pragma unroll
    for (int vv = 0; vv < 4; ++vv) {
        const int row = q0 + r0 + vv;
        ctxb[(size_t)row * 512 + h * 64 + wv * 16 + l16] =
            f2bf(pacc[vv] * rinvs[r0 + vv]);
    }
}

// ---------------------------------------------------------------------------
extern "C" void kernel_launch(void* const* d_in, const int* in_sizes, int n_in,
                              void* d_out, int out_size, void* d_ws, size_t ws_size,
                              hipStream_t stream)
{
    (void)in_sizes; (void)n_in; (void)out_size; (void)ws_size;
    const float* x  = (const float*)d_in[0];
    const float* wq = (const float*)d_in[1];
    const float* bq = (const float*)d_in[2];
    const float* wk = (const float*)d_in[3];
    const float* bk = (const float*)d_in[4];
    const float* wv = (const float*)d_in[5];
    const float* bv = (const float*)d_in[6];
    const float* wo = (const float*)d_in[7];
    const float* bo = (const float*)d_in[8];

    float* out  = (float*)d_out;                       // (S, D)
    float* attn = out + (size_t)S * D;                 // (H, S, S)

    unsigned short* qb   = (unsigned short*)d_ws;      // 4 MB each
    unsigned short* kb   = qb   + (size_t)S * D;
    unsigned short* ctxb = kb   + (size_t)S * D;
    unsigned short* vT   = ctxb + (size_t)S * D;       // 4 MB (512 x 4096)

    proj3_kernel<<<dim3(32, 8, 3), 256, 0, stream>>>(
        x, wq, bq, wk, bk, wv, bv, qb, kb, vT);
    band_attn_kernel<<<dim3(256, 8), 256, 0, stream>>>(qb, kb, vT, attn, ctxb);
    outproj_kernel<<<dim3(32, 8), 256, 0, stream>>>(ctxb, wo, bo, out);
}

// Round 20
// 146.486 us; speedup vs baseline: 1.0882x; 1.0882x over previous
//
#include <hip/hip_runtime.h>
#include <hip/hip_bf16.h>
#include <math.h>

#define S 4096
#define D 512
#define H 8
#define DK 64
#define WIN 128

typedef __attribute__((ext_vector_type(8))) short bf16x8;
typedef __attribute__((ext_vector_type(4))) float f32x4;

__device__ __forceinline__ unsigned short f2bf(float f) {
    __hip_bfloat16 h = __float2bfloat16(f);
    return *(unsigned short*)&h;
}

// ---------------------------------------------------------------------------
// fp32 -> bf16: x (y=0) and the 4 weight matrices (y=1..4). 8 elems/thread.
// ---------------------------------------------------------------------------
__global__ __launch_bounds__(256) void conv_bf16_kernel(
    const float* __restrict__ x,
    const float* __restrict__ wq, const float* __restrict__ wk,
    const float* __restrict__ wv, const float* __restrict__ wo,
    unsigned short* __restrict__ xb,
    unsigned short* __restrict__ wqb, unsigned short* __restrict__ wkb,
    unsigned short* __restrict__ wvb, unsigned short* __restrict__ wob)
{
    const float* src; unsigned short* dst; int n;
    switch (blockIdx.y) {
        case 0:  src = x;  dst = xb;  n = S * D; break;
        case 1:  src = wq; dst = wqb; n = D * D; break;
        case 2:  src = wk; dst = wkb; n = D * D; break;
        case 3:  src = wv; dst = wvb; n = D * D; break;
        default: src = wo; dst = wob; n = D * D; break;
    }
    const int i = (blockIdx.x * 256 + threadIdx.x) * 8;
    if (i >= n) return;
    float4 a = *(const float4*)&src[i];
    float4 b = *(const float4*)&src[i + 4];
    ushort4 o0 = {f2bf(a.x), f2bf(a.y), f2bf(a.z), f2bf(a.w)};
    ushort4 o1 = {f2bf(b.x), f2bf(b.y), f2bf(b.z), f2bf(b.w)};
    *(ushort4*)&dst[i]     = o0;
    *(ushort4*)&dst[i + 4] = o1;
}

// ---------------------------------------------------------------------------
// MFMA GEMM: C[m][n] = sum_e A[m][e]*W16[n][e] + bias[n]
// A, W16 bf16. B-tile (64 rows x 512 K) staged bf16 -> padded LDS.
// ---------------------------------------------------------------------------
__device__ __forceinline__ void mfma_gemm_body(
    const unsigned short* __restrict__ A,
    const unsigned short* __restrict__ W16,
    const float* __restrict__ bias,
    float* __restrict__ C,
    unsigned short* __restrict__ CB)
{
    __shared__ unsigned short Bs[64][520];

    const int tid  = threadIdx.x;
    const int m0   = blockIdx.x * 128;
    const int n0   = blockIdx.y * 64;
    const int wv   = tid >> 6;
    const int lane = tid & 63;
    const int l16  = lane & 15;
    const int klo  = (lane >> 4) * 8;

    #pragma unroll
    for (int it = 0; it < 16; ++it) {
        const int c   = tid + it * 256;
        const int row = c >> 6;
        const int kc  = (c & 63) * 8;
        *(bf16x8*)&Bs[row][kc] =
            *(const bf16x8*)&W16[(size_t)(n0 + row) * 512 + kc];
    }
    __syncthreads();

    const unsigned short* arow0 = &A[(size_t)(m0 + wv * 32 + l16) * 512 + klo];
    const unsigned short* arow1 = arow0 + 16 * 512;

    f32x4 acc[2][4];
    #pragma unroll
    for (int r = 0; r < 2; ++r)
        #pragma unroll
        for (int nf = 0; nf < 4; ++nf)
            acc[r][nf] = (f32x4){0.f, 0.f, 0.f, 0.f};

    #pragma unroll 4
    for (int kb = 0; kb < 512; kb += 32) {
        bf16x8 a0 = *(const bf16x8*)&arow0[kb];
        bf16x8 a1 = *(const bf16x8*)&arow1[kb];
        #pragma unroll
        for (int nf = 0; nf < 4; ++nf) {
            bf16x8 b = *(const bf16x8*)&Bs[nf * 16 + l16][kb + klo];
            acc[0][nf] = __builtin_amdgcn_mfma_f32_16x16x32_bf16(a0, b, acc[0][nf], 0, 0, 0);
            acc[1][nf] = __builtin_amdgcn_mfma_f32_16x16x32_bf16(a1, b, acc[1][nf], 0, 0, 0);
        }
    }

    const int r0 = (lane >> 4) * 4;
    #pragma unroll
    for (int r = 0; r < 2; ++r) {
        #pragma unroll
        for (int nf = 0; nf < 4; ++nf) {
            const int col = n0 + nf * 16 + l16;
            const float bb = bias[col];
            #pragma unroll
            for (int vv = 0; vv < 4; ++vv) {
                const int row = m0 + wv * 32 + r * 16 + r0 + vv;
                const float val = acc[r][nf][vv] + bb;
                if (C)  C [(size_t)row * 512 + col] = val;
                if (CB) CB[(size_t)row * 512 + col] = f2bf(val);
            }
        }
    }
}

__global__ __launch_bounds__(256) void proj3_kernel(
    const unsigned short* __restrict__ xb,
    const unsigned short* __restrict__ wqb, const float* __restrict__ bq,
    const unsigned short* __restrict__ wkb, const float* __restrict__ bk,
    const unsigned short* __restrict__ wvb, const float* __restrict__ bv,
    unsigned short* __restrict__ qb, unsigned short* __restrict__ kb,
    unsigned short* __restrict__ vb)
{
    const unsigned short* W; const float* b; unsigned short* CB;
    if (blockIdx.z == 0)      { W = wqb; b = bq; CB = qb; }
    else if (blockIdx.z == 1) { W = wkb; b = bk; CB = kb; }
    else                      { W = wvb; b = bv; CB = vb; }
    mfma_gemm_body(xb, W, b, nullptr, CB);
}

__global__ __launch_bounds__(256) void outproj_kernel(
    const unsigned short* __restrict__ ctxb,
    const unsigned short* __restrict__ wob, const float* __restrict__ bo,
    float* __restrict__ out)
{
    mfma_gemm_body(ctxb, wob, bo, out, nullptr);
}

// ---------------------------------------------------------------------------
// Fully fused band attention (round-13 best): MFMA QK^T -> softmax
// (P zeroed out-of-band) -> MFMA PV (V reuses the K LDS buffer) -> ctx write
// -> full-row attn write (plain coalesced stores).
// QB=16 rows/block, ~33 KB LDS -> 4 blocks/CU. Grid (256, 8).
// ---------------------------------------------------------------------------
__global__ __launch_bounds__(256) void band_attn_kernel(
    const unsigned short* __restrict__ qb, const unsigned short* __restrict__ kb,
    const unsigned short* __restrict__ vb,
    float* __restrict__ attn, unsigned short* __restrict__ ctxb)
{
    __shared__ __align__(16) unsigned short Qs[16][72];  // Qs[row][d]   (2.3 KB)
    __shared__ __align__(16) unsigned short KV[64][72];  // K:[col][d] / V^T:[d][col]
    __shared__ float P[16][336];                         // exp-scores   (21.5 KB)
    __shared__ float rinvs[16];

    const int tid = threadIdx.x;
    const int h  = blockIdx.y;
    const int q0 = blockIdx.x * 16;
    const int w0 = q0 - 128;

    const int wv   = tid >> 6;
    const int lane = tid & 63;
    const int l16  = lane & 15;
    const int klo  = (lane >> 4) * 8;
    const int r0   = (lane >> 4) * 4;

    // ---- Q staging: 16 rows x 64 d bf16 ----
    {
        const int row = tid >> 4;
        const int db  = (tid & 15) * 4;
        *(ushort4*)&Qs[row][db] =
            *(const ushort4*)&qb[(size_t)(q0 + row) * 512 + h * 64 + db];
    }

    const int lr = tid >> 2;           // stage: col/row 0..63
    const int ld = (tid & 3) * 16;     // stage: 16 d's

    // ================= QK^T phase =================
    for (int ch = 0; ch < 5; ++ch) {
        const int c0 = w0 + ch * 64;
        if (c0 + 64 <= 0 || c0 >= S) continue;   // skip fully-outside chunks
        __syncthreads();
        {
            const int krow = min(max(c0 + lr, 0), S - 1);   // clamp partials
            const unsigned short* src = &kb[(size_t)krow * 512 + h * 64 + ld];
            *(bf16x8*)&KV[lr][ld]     = *(const bf16x8*)&src[0];
            *(bf16x8*)&KV[lr][ld + 8] = *(const bf16x8*)&src[8];
        }
        __syncthreads();

        f32x4 acc = (f32x4){0.f, 0.f, 0.f, 0.f};
        #pragma unroll
        for (int kk = 0; kk < 64; kk += 32) {
            bf16x8 a = *(const bf16x8*)&Qs[l16][kk + klo];
            bf16x8 b = *(const bf16x8*)&KV[wv * 16 + l16][kk + klo];
            acc = __builtin_amdgcn_mfma_f32_16x16x32_bf16(a, b, acc, 0, 0, 0);
        }
        #pragma unroll
        for (int vv = 0; vv < 4; ++vv)
            P[r0 + vv][ch * 64 + wv * 16 + l16] = acc[vv] * 0.125f;
    }
    __syncthreads();

    // ---- softmax: exp in band, ZERO outside band (cols [0,320)) ----
    {
        const int r   = tid >> 4;
        const int lx  = tid & 15;
        const int i   = q0 + r;
        const int lo = max(i - WIN, 0) - w0;
        const int hi = min(i + WIN, S - 1) - w0;

        float m = -1e30f;
        for (int c = lo + lx; c <= hi; c += 16) m = fmaxf(m, P[r][c]);
        m = fmaxf(m, __shfl_xor(m, 1));
        m = fmaxf(m, __shfl_xor(m, 2));
        m = fmaxf(m, __shfl_xor(m, 4));
        m = fmaxf(m, __shfl_xor(m, 8));

        float sum = 0.f;
        for (int c = lx; c < 320; c += 16) {
            float e = 0.f;
            if (c >= lo && c <= hi) {
                e = __expf(P[r][c] - m);
                sum += e;
            }
            P[r][c] = e;
        }
        sum += __shfl_xor(sum, 1);
        sum += __shfl_xor(sum, 2);
        sum += __shfl_xor(sum, 4);
        sum += __shfl_xor(sum, 8);
        if (lx == 0) rinvs[r] = 1.0f / sum;
    }

    // ================= PV phase (V reuses KV buffer) =================
    f32x4 pacc = (f32x4){0.f, 0.f, 0.f, 0.f};
    for (int ch = 0; ch < 5; ++ch) {
        const int c0 = w0 + ch * 64;
        if (c0 + 64 <= 0 || c0 >= S) continue;
        __syncthreads();
        {
            const int vrow = min(max(c0 + lr, 0), S - 1);   // clamp (P=0 there)
            ushort4 v0 = *(const ushort4*)&vb[(size_t)vrow * 512 + h * 64 + ld];
            ushort4 v1 = *(const ushort4*)&vb[(size_t)vrow * 512 + h * 64 + ld + 4];
            ushort4 v2 = *(const ushort4*)&vb[(size_t)vrow * 512 + h * 64 + ld + 8];
            ushort4 v3 = *(const ushort4*)&vb[(size_t)vrow * 512 + h * 64 + ld + 12];
            KV[ld +  0][lr] = v0.x; KV[ld +  1][lr] = v0.y;
            KV[ld +  2][lr] = v0.z; KV[ld +  3][lr] = v0.w;
            KV[ld +  4][lr] = v1.x; KV[ld +  5][lr] = v1.y;
            KV[ld +  6][lr] = v1.z; KV[ld +  7][lr] = v1.w;
            KV[ld +  8][lr] = v2.x; KV[ld +  9][lr] = v2.y;
            KV[ld + 10][lr] = v2.z; KV[ld + 11][lr] = v2.w;
            KV[ld + 12][lr] = v3.x; KV[ld + 13][lr] = v3.y;
            KV[ld + 14][lr] = v3.z; KV[ld + 15][lr] = v3.w;
        }
        __syncthreads();

        #pragma unroll
        for (int kk = 0; kk < 64; kk += 32) {
            unsigned short abuf[8];
            #pragma unroll
            for (int e = 0; e < 8; ++e)
                abuf[e] = f2bf(P[l16][ch * 64 + kk + klo + e]);
            bf16x8 a = *(const bf16x8*)abuf;
            bf16x8 b = *(const bf16x8*)&KV[wv * 16 + l16][kk + klo];
            pacc = __builtin_amdgcn_mfma_f32_16x16x32_bf16(a, b, pacc, 0, 0, 0);
        }
    }

    // ---- ctx write ----
    #pragma unroll
    for (int vv = 0; vv < 4; ++vv) {
        const int row = q0 + r0 + vv;
        ctxb[(size_t)row * 512 + h * 64 + wv * 16 + l16] =
            f2bf(pacc[vv] * rinvs[r0 + vv]);
    }

    // ---- write full attn rows, coalesced; zeros outside band ----
    float* rowbase = attn + (size_t)h * S * S;
    #pragma unroll 1
    for (int r = 0; r < 16; ++r) {
        const int i = q0 + r;
        float* rowp = rowbase + (size_t)i * S;
        const int lo = max(i - WIN, 0) - w0;
        const int hi = min(i + WIN, S - 1) - w0;
        const float rv = rinvs[r];
        #pragma unroll
        for (int t = 0; t < 4; ++t) {
            const int c4 = (tid + t * 256) << 2;
            const int lc = c4 - w0;
            float4 o;
            if (lc >= lo && lc + 3 <= hi) {
                float4 p = *(const float4*)&P[r][lc];
                o.x = p.x * rv; o.y = p.y * rv; o.z = p.z * rv; o.w = p.w * rv;
            } else if (lc + 3 < lo || lc > hi) {
                o = make_float4(0.f, 0.f, 0.f, 0.f);
            } else {
                o.x = (lc + 0 >= lo && lc + 0 <= hi) ? P[r][lc + 0] * rv : 0.f;
                o.y = (lc + 1 >= lo && lc + 1 <= hi) ? P[r][lc + 1] * rv : 0.f;
                o.z = (lc + 2 >= lo && lc + 2 <= hi) ? P[r][lc + 2] * rv : 0.f;
                o.w = (lc + 3 >= lo && lc + 3 <= hi) ? P[r][lc + 3] * rv : 0.f;
            }
            *(float4*)&rowp[c4] = o;
        }
    }
}

// ---------------------------------------------------------------------------
extern "C" void kernel_launch(void* const* d_in, const int* in_sizes, int n_in,
                              void* d_out, int out_size, void* d_ws, size_t ws_size,
                              hipStream_t stream)
{
    (void)in_sizes; (void)n_in; (void)out_size; (void)ws_size;
    const float* x  = (const float*)d_in[0];
    const float* wq = (const float*)d_in[1];
    const float* bq = (const float*)d_in[2];
    const float* wk = (const float*)d_in[3];
    const float* bk = (const float*)d_in[4];
    const float* wv = (const float*)d_in[5];
    const float* bv = (const float*)d_in[6];
    const float* wo = (const float*)d_in[7];
    const float* bo = (const float*)d_in[8];

    float* out  = (float*)d_out;                       // (S, D)
    float* attn = out + (size_t)S * D;                 // (H, S, S)

    unsigned short* xb   = (unsigned short*)d_ws;      // 4 MB each
    unsigned short* qb   = xb   + (size_t)S * D;
    unsigned short* kb   = qb   + (size_t)S * D;
    unsigned short* vb   = kb   + (size_t)S * D;
    unsigned short* ctxb = vb   + (size_t)S * D;
    unsigned short* wqb  = ctxb + (size_t)S * D;       // 512 KB each
    unsigned short* wkb  = wqb  + (size_t)D * D;
    unsigned short* wvb  = wkb  + (size_t)D * D;
    unsigned short* wob  = wvb  + (size_t)D * D;

    conv_bf16_kernel<<<dim3(1024, 5), 256, 0, stream>>>(
        x, wq, wk, wv, wo, xb, wqb, wkb, wvb, wob);
    proj3_kernel<<<dim3(32, 8, 3), 256, 0, stream>>>(
        xb, wqb, bq, wkb, bk, wvb, bv, qb, kb, vb);
    band_attn_kernel<<<dim3(256, 8), 256, 0, stream>>>(qb, kb, vb, attn, ctxb);
    outproj_kernel<<<dim3(32, 8), 256, 0, stream>>>(ctxb, wob, bo, out);
}